// Round 4
// baseline (284.627 us; speedup 1.0000x reference)
//
#include <hip/hip_runtime.h>
#include <hip/hip_bf16.h>

typedef _Float16 f16;
typedef f16 f16x2 __attribute__((ext_vector_type(2)));
typedef f16 f16x4 __attribute__((ext_vector_type(4)));
typedef f16 f16x8 __attribute__((ext_vector_type(8)));
typedef float f32x2 __attribute__((ext_vector_type(2)));
typedef float f32x4 __attribute__((ext_vector_type(4)));

#define MFMA16(a, b, c) __builtin_amdgcn_mfma_f32_16x16x32_f16(a, b, c, 0, 0, 0)

__device__ __forceinline__ void glds16(const void* g, void* l) {
    __builtin_amdgcn_global_load_lds(
        (const __attribute__((address_space(1))) unsigned int*)g,
        (__attribute__((address_space(3))) unsigned int*)l, 16, 0, 0);
}

// packed f32 FMA: d = a*b + c per 32-bit half (2x f32 VALU rate)
__device__ __forceinline__ f32x2 pk_fma(f32x2 a, f32x2 b, f32x2 c) {
    f32x2 d;
    asm("v_pk_fma_f32 %0, %1, %2, %3" : "=v"(d) : "v"(a), "v"(b), "v"(c));
    return d;
}

// ---------------- f32 -> f16 convert ----------------
__global__ __launch_bounds__(256) void cvt_kernel(const float* __restrict__ s,
                                                  f16* __restrict__ d, int n) {
    int i = (blockIdx.x * 256 + threadIdx.x) * 8;
    if (i >= n) return;
    float4 a = *(const float4*)(s + i);
    float4 b = *(const float4*)(s + i + 4);
    f16x8 h;
    h[0] = (f16)a.x; h[1] = (f16)a.y; h[2] = (f16)a.z; h[3] = (f16)a.w;
    h[4] = (f16)b.x; h[5] = (f16)b.y; h[6] = (f16)b.z; h[7] = (f16)b.w;
    *(f16x8*)(d + i) = h;
}

// ---------------- GEMM: C[M,N] = A[M,K] @ B[N,K]^T + bias ----------------
// 128x128 tile, BK=32, 4 waves (2x2). XCD-swizzled blockIdx: the 8 nb-blocks
// sharing one A-panel are logical-consecutive on one XCD -> A-panel L2-reuse.
template <bool A_F32, bool OUT_F16>
__global__ __launch_bounds__(256) void gemm_bt_kernel(
    const void* __restrict__ A_, const f16* __restrict__ Bw,
    const float* __restrict__ bias, void* __restrict__ C_, int M, int N, int K) {
    __shared__ f16 As[128 * 32];
    __shared__ f16 Bs[128 * 32];
    const int tid = threadIdx.x;
    const int lane = tid & 63;
    const int w = tid >> 6;
    const int nblk = N >> 7;
    const int cpx = (int)gridDim.x >> 3;
    const int logical = ((int)blockIdx.x & 7) * cpx + ((int)blockIdx.x >> 3);
    const int mb = logical / nblk, nb = logical % nblk;
    const int wm = w >> 1, wn = w & 1;
    const int q = lane >> 4, cl = lane & 15;

    const f16* Bbase = Bw + (size_t)nb * 128 * K;
    const float* A32 = (const float*)A_;
    const f16* A16 = (const f16*)A_;

    f32x4 acc[4][4] = {};

#pragma unroll 1
    for (int kt = 0; kt < (K >> 5); ++kt) {
        const int k0 = kt << 5;
#pragma unroll
        for (int it = 0; it < 2; ++it) {
            int c = it * 256 + w * 64 + lane;
            glds16(Bbase + (size_t)(c >> 2) * K + k0 + (c & 3) * 8,
                   &Bs[(it * 256 + w * 64) * 8]);
        }
        if (A_F32) {
#pragma unroll
            for (int it = 0; it < 2; ++it) {
                int c = tid + it * 256;
                int row = c >> 2, kc = c & 3;
                const float* sp = A32 + (size_t)(mb * 128 + row) * K + k0 + kc * 8;
                float4 a = *(const float4*)sp;
                float4 b = *(const float4*)(sp + 4);
                f16x8 h;
                h[0] = (f16)a.x; h[1] = (f16)a.y; h[2] = (f16)a.z; h[3] = (f16)a.w;
                h[4] = (f16)b.x; h[5] = (f16)b.y; h[6] = (f16)b.z; h[7] = (f16)b.w;
                *(f16x8*)&As[c * 8] = h;
            }
        } else {
#pragma unroll
            for (int it = 0; it < 2; ++it) {
                int c = it * 256 + w * 64 + lane;
                glds16(A16 + (size_t)(mb * 128 + (c >> 2)) * K + k0 + (c & 3) * 8,
                       &As[(it * 256 + w * 64) * 8]);
            }
        }
        __syncthreads();
        f16x8 af[4], bf[4];
#pragma unroll
        for (int mt = 0; mt < 4; ++mt)
            af[mt] = *(const f16x8*)&As[(wm * 64 + mt * 16 + cl) * 32 + q * 8];
#pragma unroll
        for (int nt = 0; nt < 4; ++nt)
            bf[nt] = *(const f16x8*)&Bs[(wn * 64 + nt * 16 + cl) * 32 + q * 8];
#pragma unroll
        for (int mt = 0; mt < 4; ++mt)
#pragma unroll
            for (int nt = 0; nt < 4; ++nt)
                acc[mt][nt] = MFMA16(af[mt], bf[nt], acc[mt][nt]);
        __syncthreads();
    }
    float bv[4];
#pragma unroll
    for (int nt = 0; nt < 4; ++nt) bv[nt] = bias[nb * 128 + wn * 64 + nt * 16 + cl];
#pragma unroll
    for (int mt = 0; mt < 4; ++mt) {
#pragma unroll
        for (int nt = 0; nt < 4; ++nt) {
            size_t gr = (size_t)(mb * 128 + wm * 64 + mt * 16 + q * 4);
            int gc = nb * 128 + wn * 64 + nt * 16 + cl;
#pragma unroll
            for (int r = 0; r < 4; ++r) {
                float v = acc[mt][nt][r] + bv[nt];
                if (OUT_F16)
                    ((f16*)C_)[(gr + r) * N + gc] = (f16)v;
                else
                    ((float*)C_)[(gr + r) * N + gc] = v;
            }
        }
    }
}

// ---------------- segment-average partials ----------------
__global__ __launch_bounds__(256) void avg_kernel(const f16* __restrict__ X1h,
                                                  float* __restrict__ partial) {
    const int bn = blockIdx.x >> 2, rc = blockIdx.x & 3;
    const int tid = threadIdx.x;
    const f16* base = X1h + (size_t)bn * 262144 + (size_t)rc * 65536 + tid * 4;
    float s0 = 0.f, s1 = 0.f, s2 = 0.f, s3 = 0.f;
    for (int l = 0; l < 64; ++l) {
        f16x4 v = *(const f16x4*)(base + (size_t)l * 1024);
        s0 += (float)v[0]; s1 += (float)v[1]; s2 += (float)v[2]; s3 += (float)v[3];
    }
    const float sc = 1.f / 256.f;
    float4 o = make_float4(s0 * sc, s1 * sc, s2 * sc, s3 * sc);
    *(float4*)(partial + (size_t)(bn * 4 + rc) * 1024 + tid * 4) = o;
}

// ---------------- router ----------------
__global__ __launch_bounds__(64) void router_kernel(const float* __restrict__ partial,
                                                    const float* __restrict__ emb,
                                                    float* __restrict__ ew) {
    const int t = blockIdx.x;
    const int bn = t >> 3, h = t & 7;
    const int lane = threadIdx.x;
    float acc = 0.f;
    const float* p = partial + (size_t)bn * 4096 + h * 128;
    if (lane < 16) {
        for (int d = 0; d < 128; ++d) {
            float a = p[d] + p[d + 1024] + p[d + 2048] + p[d + 3072];
            acc = fmaf(a, emb[d * 16 + lane], acc);
        }
    }
    float m = acc;
#pragma unroll
    for (int o = 8; o; o >>= 1) m = fmaxf(m, __shfl_xor(m, o));
    float pr = __expf(acc - m);
    float s = pr;
#pragma unroll
    for (int o = 8; o; o >>= 1) s += __shfl_xor(s, o);
    if (lane < 16) ew[t * 16 + lane] = pr / s;
}

// ---------------- expert mixture (pk_fma version) ----------------
__global__ __launch_bounds__(256) void mix_kernel(const float* __restrict__ ew,
                                                  const float* __restrict__ FL,
                                                  const float* __restrict__ SL,
                                                  f16* __restrict__ m1h,
                                                  f16* __restrict__ m2h) {
    __shared__ f32x2 ews2[4096];  // [tt][e] duplicated {w,w}, 32KB
    const int bid = blockIdx.x;
    const int which = bid >> 8, th = (bid >> 7) & 1, chunk = bid & 127;
    const float* src = which ? SL : FL;
    f16* dst = which ? m2h : m1h;
    const int tid = threadIdx.x;
    const int e0 = chunk * 512 + tid * 2;
    f32x2 fl[16];
#pragma unroll
    for (int e = 0; e < 16; ++e)
        fl[e] = *(const f32x2*)(src + (size_t)e * 65536 + e0);
    for (int i = tid; i < 4096; i += 256) {
        float wv = ew[th * 4096 + i];
        f32x2 p; p.x = wv; p.y = wv;
        ews2[i] = p;
    }
    __syncthreads();
#pragma unroll 1
    for (int tt = 0; tt < 256; ++tt) {
        f32x2 a; a.x = 0.f; a.y = 0.f;
#pragma unroll
        for (int e = 0; e < 16; ++e)
            a = pk_fma(ews2[tt * 16 + e], fl[e], a);
        f16x2 h;
        h[0] = (f16)a.x; h[1] = (f16)a.y;
        *(f16x2*)(dst + (size_t)(th * 256 + tt) * 65536 + e0) = h;
    }
}

// ---------------- MLP: LDS-streamed weights ----------------
__device__ __forceinline__ void stage_w128(const f16* __restrict__ src, f16* lds,
                                           int w, int lane, int rowstride) {
#pragma unroll
    for (int it = 0; it < 8; ++it) {
        int cbase = it * 256 + w * 64;
        int c = cbase + lane;
        int row = c >> 4, pc = c & 15;
        int lc = pc ^ (row & 7);
        glds16(src + (size_t)row * rowstride + lc * 8, lds + cbase * 8);
    }
}

__global__ __launch_bounds__(256) void mlp_kernel(const f16* __restrict__ Xg,
                                                  const f16* __restrict__ m1h,
                                                  const f16* __restrict__ m2h,
                                                  f16* __restrict__ Yg) {
    __shared__ f16 Hs[128 * 128];
    __shared__ f16 Ws[128 * 128];
    // XCD swizzle over 1024 blocks (= 512 tiles x 2 halves): lh pair colocates
    const int cpx = (int)gridDim.x >> 3;
    const int logical = ((int)blockIdx.x & 7) * cpx + ((int)blockIdx.x >> 3);
    const int t = logical >> 1, lh = logical & 1;
    const int n = (t >> 3) & 15;
    const int tm = (n > 0) ? (t - 8) : t;
    const int tid = threadIdx.x;
    const int lane = tid & 63, w = tid >> 6;
    const int q = lane >> 4, cl = lane & 15;
    const int l0 = w * 32;

    const f16* Xsrc = Xg + (size_t)t * 32768 + lh * 16384;
    const f16* m1b = m1h + (size_t)tm * 65536;
    const f16* m2b = m2h + (size_t)tm * 65536;

    f16x8 xf[2][4];
#pragma unroll
    for (int lt = 0; lt < 2; ++lt) {
        int l = l0 + lt * 16 + cl;
#pragma unroll
        for (int ks = 0; ks < 4; ++ks)
            xf[lt][ks] = *(const f16x8*)(Xsrc + (size_t)l * 128 + ks * 32 + q * 8);
    }
    stage_w128(m1b, Ws, w, lane, 128);
    __syncthreads();

    f32x4 acc2[2][8] = {};
#pragma unroll 1
    for (int ic = 0; ic < 4; ++ic) {
        // ---- stage1: h^T over i-chunk, Ws = m1[ic] ----
#pragma unroll
        for (int it = 0; it < 8; ++it) {
            f16x8 af[4];
#pragma unroll
            for (int ks = 0; ks < 4; ++ks) {
                int r = it * 16 + cl;
                int ch = (ks * 4 + q) ^ (r & 7);
                af[ks] = *(const f16x8*)&Ws[r * 128 + ch * 8];
            }
            f32x4 a1[2] = {};
#pragma unroll
            for (int ks = 0; ks < 4; ++ks)
#pragma unroll
                for (int lt = 0; lt < 2; ++lt)
                    a1[lt] = MFMA16(af[ks], xf[lt][ks], a1[lt]);
            int ibase = it * 16 + q * 4;
            int ch = ibase >> 3;
            int sub = (q & 1) * 8;
#pragma unroll
            for (int lt = 0; lt < 2; ++lt) {
                int l = l0 + lt * 16 + cl;
                f16x4 hv;
                hv[0] = (f16)fmaxf(a1[lt][0], 0.f);
                hv[1] = (f16)fmaxf(a1[lt][1], 0.f);
                hv[2] = (f16)fmaxf(a1[lt][2], 0.f);
                hv[3] = (f16)fmaxf(a1[lt][3], 0.f);
                *(f16x4*)((char*)Hs + (size_t)l * 256 + ((ch ^ (l & 7)) << 4) + sub) = hv;
            }
        }
        __syncthreads();
        stage_w128(m2b + ic * 128, Ws, w, lane, 512);
        __syncthreads();

        // ---- stage2: acc2 += h @ m2[ic]^T ----
        f16x8 hf[2][4];
#pragma unroll
        for (int lt = 0; lt < 2; ++lt) {
            int l = l0 + lt * 16 + cl;
#pragma unroll
            for (int ks = 0; ks < 4; ++ks) {
                int ch = (ks * 4 + q) ^ (l & 7);
                hf[lt][ks] = *(const f16x8*)&Hs[l * 128 + ch * 8];
            }
        }
#pragma unroll
        for (int nt = 0; nt < 8; ++nt) {
            f16x8 bf[4];
#pragma unroll
            for (int ks = 0; ks < 4; ++ks) {
                int r = nt * 16 + cl;
                int ch = (ks * 4 + q) ^ (r & 7);
                bf[ks] = *(const f16x8*)&Ws[r * 128 + ch * 8];
            }
#pragma unroll
            for (int lt = 0; lt < 2; ++lt)
#pragma unroll
                for (int ks = 0; ks < 4; ++ks)
                    acc2[lt][nt] = MFMA16(hf[lt][ks], bf[ks], acc2[lt][nt]);
        }
        __syncthreads();
        if (ic < 3) {
            stage_w128(m1b + (size_t)(ic + 1) * 16384, Ws, w, lane, 128);
            __syncthreads();
        }
    }
    f16* Yb = Yg + (size_t)t * 32768 + lh * 16384;
#pragma unroll
    for (int lt = 0; lt < 2; ++lt) {
#pragma unroll
        for (int nt = 0; nt < 8; ++nt) {
            int lr = l0 + lt * 16 + q * 4;
            int d = nt * 16 + cl;
#pragma unroll
            for (int r = 0; r < 4; ++r)
                Yb[(size_t)(lr + r) * 128 + d] = (f16)acc2[lt][nt][r];
        }
    }
}

extern "C" void kernel_launch(void* const* d_in, const int* in_sizes, int n_in,
                              void* d_out, int out_size, void* d_ws, size_t ws_size,
                              hipStream_t stream) {
    const float* x    = (const float*)d_in[0];
    const float* W_mh = (const float*)d_in[1];
    const float* b_mh = (const float*)d_in[2];
    const float* W_mg = (const float*)d_in[3];
    const float* b_mg = (const float*)d_in[4];
    const float* emb  = (const float*)d_in[5];
    const float* FL   = (const float*)d_in[6];
    const float* SL   = (const float*)d_in[7];

    char* ws = (char*)d_ws;
    f16*   X1h  = (f16*)(ws + 0);
    f16*   m1h  = (f16*)(ws + 33554432);
    f16*   m2h  = (f16*)(ws + 100663296);
    f16*   Wmhh = (f16*)(ws + 167772160);
    f16*   Wmgh = (f16*)(ws + 169869312);
    float* part = (float*)(ws + 171966464);
    float* ew   = (float*)(ws + 173015040);

    cvt_kernel<<<512, 256, 0, stream>>>(W_mh, Wmhh, 1048576);
    cvt_kernel<<<512, 256, 0, stream>>>(W_mg, Wmgh, 1048576);
    gemm_bt_kernel<true, true><<<1024, 256, 0, stream>>>(x, Wmhh, b_mh, X1h,
                                                         16384, 1024, 1024);
    avg_kernel<<<256, 256, 0, stream>>>(X1h, part);
    router_kernel<<<512, 64, 0, stream>>>(part, emb, ew);
    mix_kernel<<<512, 256, 0, stream>>>(ew, FL, SL, m1h, m2h);
    mlp_kernel<<<1024, 256, 0, stream>>>(X1h, m1h, m2h, X1h);
    gemm_bt_kernel<false, false><<<1024, 256, 0, stream>>>(X1h, Wmgh, b_mg, d_out,
                                                           16384, 1024, 1024);
}